// Round 5
// baseline (128.735 us; speedup 1.0000x reference)
//
#include <hip/hip_runtime.h>
#include <hip/hip_bf16.h>
#include <stdint.h>

// Problem constants (B=1)
#define NN   256     // MSA depth (contraction K of GEMM1)
#define LL   192
#define MDIM 6144    // L*J
#define D2   1024    // J*J
#define FF   128     // n_feat_out

typedef __bf16 bf16x8 __attribute__((ext_vector_type(8)));
typedef float  f32x4  __attribute__((ext_vector_type(4)));
typedef float  f32x16 __attribute__((ext_vector_type(16)));

#define MFMA16(a, b, c) __builtin_amdgcn_mfma_f32_16x16x32_bf16(a, b, c, 0, 0, 0)
#define MFMA32(a, b, c) __builtin_amdgcn_mfma_f32_32x32x16_bf16(a, b, c, 0, 0, 0)

__device__ __forceinline__ void gload_lds16(const void* g, void* l) {
  __builtin_amdgcn_global_load_lds(
      (__attribute__((address_space(1))) void*)(g),
      (__attribute__((address_space(3))) void*)(l),
      16, 0, 0);
}

static __device__ __forceinline__ unsigned short bf16_bits(float v) {
  __bf16 h = (__bf16)v;
  return __builtin_bit_cast(unsigned short, h);
}

// ---------------------------------------------------------------------------
// prep_all v2 (unchanged from R4): 64x64 tiles, ILP=4, padded [64][65] LDS.
//  blocks [0,384):   transpose x_down  [256][6144] f32 -> At [6144][256] bf16
//  blocks [384,768): transpose x_down_w            -> Bt
//  blocks [768,896): WB[fragment-linear] = bf16(a2*W), S = colsum, T = b2@W+b
// ---------------------------------------------------------------------------
__global__ __launch_bounds__(256)
void prep_all(const float* __restrict__ x1, const float* __restrict__ x2,
              const float* __restrict__ W, const float* __restrict__ a2,
              const float* __restrict__ b2, const float* __restrict__ bias,
              __bf16* __restrict__ At, __bf16* __restrict__ Bt,
              __bf16* __restrict__ WB, float* __restrict__ S,
              float* __restrict__ T) {
  __shared__ float tile[64][65];
  const int b = blockIdx.x;
  const int t = threadIdx.x;
  if (b < 768) {
    const float* src = (b < 384) ? x1 : x2;
    __bf16* dst = (b < 384) ? At : Bt;
    const int bb = (b < 384) ? b : b - 384;
    const int m0 = (bb % 96) * 64;
    const int k0 = (bb / 96) * 64;
    const int rr = t >> 4;
    const int cc = (t & 15) * 4;
#pragma unroll
    for (int it = 0; it < 4; ++it) {
      const int kr = rr + it * 16;
      const float4 v = *(const float4*)&src[(size_t)(k0 + kr) * MDIM + m0 + cc];
      tile[kr][cc + 0] = v.x;
      tile[kr][cc + 1] = v.y;
      tile[kr][cc + 2] = v.z;
      tile[kr][cc + 3] = v.w;
    }
    __syncthreads();
#pragma unroll
    for (int it = 0; it < 4; ++it) {
      const int mr = rr + it * 16;
      ushort4 u;
      u.x = bf16_bits(tile[cc + 0][mr]);
      u.y = bf16_bits(tile[cc + 1][mr]);
      u.z = bf16_bits(tile[cc + 2][mr]);
      u.w = bf16_bits(tile[cc + 3][mr]);
      *(ushort4*)&dst[(size_t)(m0 + mr) * NN + k0 + cc] = u;
    }
  } else {
    const int f = b - 768;
    float s = 0.f, tt = 0.f;
#pragma unroll
    for (int it = 0; it < 4; ++it) {
      const int k = t + it * 256;
      const float wv = W[(size_t)k * FF + f];
      const __bf16 wa = (__bf16)(a2[k] * wv);
      WB[(size_t)(k >> 5) * 4096 + f * 32 + ((k >> 3) & 3) * 8 + (k & 7)] = wa;
      s += (float)wa;
      tt += b2[k] * wv;
    }
#pragma unroll
    for (int off = 32; off; off >>= 1) {
      s += __shfl_xor(s, off);
      tt += __shfl_xor(tt, off);
    }
    const int wv_ = t >> 6, ln = t & 63;
    if (ln == 0) { tile[0][wv_] = s; tile[1][wv_] = tt; }
    __syncthreads();
    if (t == 0) {
      S[f] = tile[0][0] + tile[0][1] + tile[0][2] + tile[0][3];
      T[f] = tile[1][0] + tile[1][1] + tile[1][2] + tile[1][3] + bias[f];
    }
  }
}

// ---------------------------------------------------------------------------
// fused14 = fused10 with GEMM1 moved to mfma_f32_32x32x16_bf16.
// Motivation (R4 counters): schedule experiments exhausted (fused11/12/13 all
// regressed; fused10 is the local optimum at 52.9us with all pipes <31%).
// 32x32x16 gives: 2382-2495 TF vs 2075-2176 (measured ubench) = ~10-15% less
// matrix-pipe occupancy for identical FLOPs; MFMA instr count halves
// (1024->512/block), freeing issue slots. ds_read count UNCHANGED (16 b128/kb).
// Staging, swizzle, barriers, GEMM2, epilogue: byte-identical to fused10.
//   - C/D layout 32x32 (HW-verified): col=lane&31, row=(reg&3)+8*(reg>>2)
//     +4*(lane>>5). One 32x32 frag = one COMPLETE LN row (i,l fixed; all j,m)
//     -> LN reduce is a clean full-wave butterfly; scatter re-derived to
//     produce the IDENTICAL Xs content (same G-swizzle), so GEMM2 is untouched.
//   - Frag reads: row = base + frag*32 + (lane&31), k-group = ks*2+(lane>>5),
//     slot = (kgroup ^ (row&7))*16 -> same store-side swizzle, 8 lanes/quad
//     aggregate-optimal (same as fused10).
//   - Scatter banks: 2 lanes/bank (free). Tripwires: WRITE_SIZE == 18432 KB,
//     VGPR <= 64, conflicts ~2.9M, absmax 0.015625.
// out = rstd*(x@Wa - mean*S) + T
// ---------------------------------------------------------------------------
__global__ __launch_bounds__(512, 4)
void fused14(const __bf16* __restrict__ At, const __bf16* __restrict__ Bt,
             const __bf16* __restrict__ WB, const float* __restrict__ S,
             const float* __restrict__ T, float* __restrict__ out) {
  __shared__ uint8_t lds[65536];      // staging (A 16K @0, B 32K @16K) / Xs[32][2048]
  __shared__ float mean_s[32], rstd_s[32];

  const int tid = threadIdx.x;
  const int w = tid >> 6;            // wave 0..7
  const int lane = tid & 63;
  const int q = lane >> 4;           // quad (GEMM2)
  const int c = lane & 15;           // (GEMM2)
  const int c5 = lane & 31;          // 32x32 col
  const int hi = lane >> 5;          // 32x32 k-half

  // ---- XCD banding: b&7 = XCD (round-robin dispatch), 12x12 rectangle ----
  const int b = blockIdx.x;
  const int xcd = b & 7;
  const int s_ = b >> 3;             // 0..143
  const int bx = (xcd >> 1) * 12 + (s_ % 12);   // 0..47  (m, 128-wide)
  const int by = (xcd & 1) * 12 + (s_ / 12);    // 0..23  (n, 256-wide)
  const int m0 = bx * 128, n0 = by * 256;

  uint8_t* As = lds;                 // 128 rows x 128B
  uint8_t* Bs = lds + 16384;         // 256 rows x 128B

  // staging lane decomposition: 8 lanes per 128B row (BK=64 bf16)
  const int l8 = lane & 7;
  const int r8 = lane >> 3;
  const int gsw = l8 ^ r8;           // XOR-swizzled source 16B-group

  f32x16 acc[2][2];
  acc[0][0] = (f32x16){0.f};
  acc[0][1] = (f32x16){0.f};
  acc[1][0] = (f32x16){0.f};
  acc[1][1] = (f32x16){0.f};

  const int mbase = (w & 1) * 64;    // wave grid 2(m) x 4(n)
  const int nbase = (w >> 1) * 64;

  // ---------------- GEMM1 K-loop: 4 chunks of BK=64 (rolled) ----------------
  {
    const __bf16* gA = At + (size_t)(m0 + w * 16 + r8) * NN + gsw * 8;
    const __bf16* gB = Bt + (size_t)(n0 + w * 32 + r8) * NN + gsw * 8;
#pragma unroll 1
    for (int kb = 0; kb < 4; ++kb) {
      __syncthreads();
      // A: 16 rows/wave (2 instr), B: 32 rows/wave (4 instr)
#pragma unroll
      for (int j = 0; j < 2; ++j)
        gload_lds16(gA + (size_t)j * 8 * NN, As + (w * 16 + j * 8) * 128);
#pragma unroll
      for (int j = 0; j < 4; ++j)
        gload_lds16(gB + (size_t)j * 8 * NN, Bs + (w * 32 + j * 8) * 128);
      __syncthreads();
      // 4 x 16-k steps; lane reads its 8-k half: kgroup = ks*2 + hi
#pragma unroll
      for (int ks = 0; ks < 4; ++ks) {
        const int slot = ((ks * 2 + hi) ^ l8) * 16;
        bf16x8 a0 = *(const bf16x8*)(As + (mbase + c5) * 128 + slot);
        bf16x8 a1 = *(const bf16x8*)(As + (mbase + 32 + c5) * 128 + slot);
        bf16x8 b0 = *(const bf16x8*)(Bs + (nbase + c5) * 128 + slot);
        bf16x8 b1 = *(const bf16x8*)(Bs + (nbase + 32 + c5) * 128 + slot);
        acc[0][0] = MFMA32(a0, b0, acc[0][0]);
        acc[1][0] = MFMA32(a1, b0, acc[1][0]);
        acc[0][1] = MFMA32(a0, b1, acc[0][1]);
        acc[1][1] = MFMA32(a1, b1, acc[1][1]);
      }
      gA += 64;
      gB += 64;
    }
  }

  // ------------- GEMM2 depth-2 prefetch (held shallow while acc is live) -----
  const int fs = w * 16;             // this wave's 16-f slice
  const __bf16* wbp = WB + (fs + c) * 32 + q * 8;   // + kstep*4096 elements
  bf16x8 pb[8];
  pb[0] = *(const bf16x8*)(wbp);
  pb[1] = *(const bf16x8*)(wbp + 4096);

  __syncthreads();   // all staging ds_reads done; lds becomes Xs[32][2048]

  // ------------- LN stats + scatter (32x32 frag = one full LN row) ----------
  // Xs byte addr for element (row r, k): g=k>>3; G = g ^ (g>>4) ^ (r&7);
  // addr = r*2048 + G*16 + (k&7)*2  — identical map to fused10.
  // Value at lane (hi,c5), reg: C[j][m], j=(reg&3)+8*(reg>>2)+4*hi, m=c5.
  const int i_hi = w & 1, l_hi = w >> 1;
  const int p = lane & 1;
  const int m0w = c5 & 30;           // even m of the lane pair
#pragma unroll
  for (int fm = 0; fm < 2; ++fm) {
#pragma unroll
    for (int fn = 0; fn < 2; ++fn) {
      float s1 = 0.f, s2 = 0.f;
#pragma unroll
      for (int reg = 0; reg < 16; ++reg) {
        const float v = acc[fm][fn][reg];
        s1 += v; s2 += v * v;
      }
#pragma unroll
      for (int off = 32; off; off >>= 1) {
        s1 += __shfl_xor(s1, off);
        s2 += __shfl_xor(s2, off);
      }
      const float mean = s1 * (1.0f / 1024.0f);
      const float var = s2 * (1.0f / 1024.0f) - mean * mean;
      const float rstd = rsqrtf(var + 1e-5f);
      const int r = (i_hi * 2 + fm) * 8 + l_hi * 2 + fn;   // 0..31
      if (lane == 0) { mean_s[r] = mean; rstd_s[r] = rstd; }
      const int r7 = r & 7;
      // pack (m0, m0+1) bf16 pairs: even lane writes even regs' rows,
      // odd lane writes odd regs' rows; 2 shfl + 1 write per reg-pair.
#pragma unroll
      for (int reg8 = 0; reg8 < 8; ++reg8) {
        const float x = acc[fm][fn][2 * reg8];       // row j(2*reg8), own m
        const float y = acc[fm][fn][2 * reg8 + 1];   // row j(2*reg8+1), own m
        const float rx = __shfl_xor(x, 1);
        const float ry = __shfl_xor(y, 1);
        const int j_w = 2 * (reg8 & 1) + p + 8 * (reg8 >> 1) + 4 * hi;
        const int k = j_w * 32 + m0w;
        const int g = k >> 3;
        const int G = g ^ (g >> 4) ^ r7;
        const uint32_t dw =
            p ? (((uint32_t)bf16_bits(y) << 16) | (uint32_t)bf16_bits(ry))
              : (((uint32_t)bf16_bits(rx) << 16) | (uint32_t)bf16_bits(x));
        *(uint32_t*)(lds + r * 2048 + G * 16 + (m0w & 7) * 2) = dw;
      }
    }
  }

  __syncthreads();   // Xs + stats visible; acc DEAD below
  __builtin_amdgcn_sched_barrier(0);   // pin the deepening loads BELOW here

  // ------------- deepen WB pipeline to 8 (acc registers freed) -------------
#pragma unroll
  for (int pp = 2; pp < 8; ++pp)
    pb[pp] = *(const bf16x8*)(wbp + pp * 4096);

  // ------------- GEMM2: Xs(32x1024) @ Wa^T -> 32x16 (per wave), depth-8 ------
  f32x4 acc2[2];
  acc2[0] = (f32x4){0.f, 0.f, 0.f, 0.f};
  acc2[1] = (f32x4){0.f, 0.f, 0.f, 0.f};
  const int c7 = c & 7;
#pragma unroll
  for (int kstep = 0; kstep < 32; ++kstep) {
    const int g = kstep * 4 + q;
    const int G = g ^ (g >> 4) ^ c7;
    const bf16x8 a0 = *(const bf16x8*)(lds + c * 2048 + G * 16);
    const bf16x8 a1 = *(const bf16x8*)(lds + (16 + c) * 2048 + G * 16);
    acc2[0] = MFMA16(a0, pb[kstep & 7], acc2[0]);
    acc2[1] = MFMA16(a1, pb[kstep & 7], acc2[1]);
    if (kstep < 24)
      pb[kstep & 7] = *(const bf16x8*)(wbp + (kstep + 8) * 4096);
  }

  // ------------- epilogue: affine + store (S/T loaded only now) -------------
  const float S0 = S[fs + c], T0 = T[fs + c];
#pragma unroll
  for (int reg = 0; reg < 4; ++reg) {
    const int r0 = q * 4 + reg;            // LN rows 0..15 (acc2[0])
    const int r1 = 16 + r0;                // LN rows 16..31 (acc2[1])
    {
      const float mean = mean_s[r0], rstd = rstd_s[r0];
      const int i = bx * 4 + (r0 >> 3);
      const int l = by * 8 + (r0 & 7);
      out[((size_t)i * LL + l) * FF + fs + c] =
          rstd * (acc2[0][reg] - mean * S0) + T0;
    }
    {
      const float mean = mean_s[r1], rstd = rstd_s[r1];
      const int i = bx * 4 + (r1 >> 3);
      const int l = by * 8 + (r1 & 7);
      out[((size_t)i * LL + l) * FF + fs + c] =
          rstd * (acc2[1][reg] - mean * S0) + T0;
    }
  }
}

// ---------------------------------------------------------------------------
extern "C" void kernel_launch(void* const* d_in, const int* in_sizes, int n_in,
                              void* d_out, int out_size, void* d_ws, size_t ws_size,
                              hipStream_t stream) {
  const float* x_down   = (const float*)d_in[0];
  const float* x_down_w = (const float*)d_in[1];
  const float* a2       = (const float*)d_in[2];
  const float* b2       = (const float*)d_in[3];
  const float* W        = (const float*)d_in[4];
  const float* bias     = (const float*)d_in[5];
  float* out = (float*)d_out;

  uint8_t* ws = (uint8_t*)d_ws;
  __bf16* At  = (__bf16*)(ws);                 // 6144*256*2 = 3145728 B
  __bf16* Bt  = (__bf16*)(ws + 3145728);       // 3145728 B
  __bf16* WB  = (__bf16*)(ws + 6291456);       // 128*1024*2 = 262144 B
  float*  S   = (float*)(ws + 6553600);        // 512 B
  float*  T   = (float*)(ws + 6554112);        // 512 B

  prep_all<<<dim3(896), dim3(256), 0, stream>>>(x_down, x_down_w, W, a2, b2,
                                                bias, At, Bt, WB, S, T);
  fused14<<<dim3(1152), dim3(512), 0, stream>>>(At, Bt, WB, S, T, out);
}